// Round 19
// baseline (318.232 us; speedup 1.0000x reference)
//
#include <hip/hip_runtime.h>
#include <math.h>

typedef unsigned short u16;
typedef __bf16 bf16_t;
typedef bf16_t bf16x8 __attribute__((ext_vector_type(8)));
typedef float f32x4 __attribute__((ext_vector_type(4)));
typedef float f32x16 __attribute__((ext_vector_type(16)));

#define DI __device__ __forceinline__

DI u16 f2bf(float f) {
  union { float f; unsigned u; } c; c.f = f;
  unsigned r = c.u + 0x7FFFu + ((c.u >> 16) & 1u);
  return (u16)(r >> 16);
}

DI unsigned cvt_pk(float lo, float hi_) {  // dst[15:0]=bf16(lo), dst[31:16]=bf16(hi_)
  unsigned d;
  asm("v_cvt_pk_bf16_f32 %0, %1, %2" : "=v"(d) : "v"(lo), "v"(hi_));
  return d;
}

DI void swap32(unsigned& a, unsigned& b) {  // a.hi <-> b.lo (lanes 32-63 of a with 0-31 of b)
  asm volatile("v_permlane32_swap_b32 %0, %1" : "+v"(a), "+v"(b));
}

typedef __attribute__((address_space(1))) void* gas_ptr;
typedef __attribute__((address_space(3))) void* las_ptr;

DI void gload16(const void* g, void* l) {
  __builtin_amdgcn_global_load_lds((gas_ptr)g, (las_ptr)l, 16, 0, 0);
}

// ------- fused pre-pass: 12 weight transposes + enc cvt + bias packing in ONE launch ------
struct TransArgs {
  const float* src[12]; u16* dst[12];
  const float* enc; u16* encb;
  float* bq; float* bc;
  const float* qb; const float* kb; const float* vb; const float* ckb; const float* cvb;
};
__global__ __launch_bounds__(256) void k_prepass(TransArgs ta) {
  int bx = blockIdx.x;
  if (bx >= 8192) {                   // ---- biaspack (20 blocks) ----
    int i = (bx - 8192) * 256 + threadIdx.x;
    if (i < 1024) ta.bq[i] = ta.qb[i];
    else if (i < 2048) ta.bq[i] = ta.kb[i - 1024];
    else if (i < 3072) ta.bq[i] = ta.vb[i - 2048];
    else if (i < 4096) ta.bc[i - 3072] = ta.ckb[i - 3072];
    else if (i < 5120) ta.bc[i - 3072] = ta.cvb[i - 4096];
    return;
  }
  if (bx >= 6144) {                   // ---- enc cvt ----
    int i = (bx - 6144) * 256 + threadIdx.x;
    float4 v = ((const float4*)ta.enc)[i];
    ushort4 o;
    o.x = f2bf(v.x); o.y = f2bf(v.y); o.z = f2bf(v.z); o.w = f2bf(v.w);
    ((ushort4*)ta.encb)[i] = o;
    return;
  }
  // ---- transpose: w [K][N] f32 -> wt [N][K] bf16, 64x64 tiles ----
  __shared__ float tileT[64][65];
  int z, local, K, N;
  if (bx < 2048) { z = bx >> 8; local = bx & 255; K = 1024; N = 1024; }
  else {
    int i = bx - 2048; z = 8 + (i >> 10); local = i & 1023;
    if (z & 1) { K = 4096; N = 1024; } else { K = 1024; N = 4096; }
  }
  const float* w = ta.src[z];
  u16* wt = ta.dst[z];
  const int nT = N >> 6;
  const int n0 = (local % nT) * 64, k0 = (local / nT) * 64;

  const int krow = threadIdx.x >> 4, c4 = threadIdx.x & 15;
#pragma unroll
  for (int i = 0; i < 4; ++i) {
    int kr = krow + i * 16;
    float4 v = *(const float4*)(w + (size_t)(k0 + kr) * N + n0 + c4 * 4);
    tileT[c4 * 4 + 0][kr] = v.x;
    tileT[c4 * 4 + 1][kr] = v.y;
    tileT[c4 * 4 + 2][kr] = v.z;
    tileT[c4 * 4 + 3][kr] = v.w;
  }
  __syncthreads();
  const int nrow = threadIdx.x >> 2, kq = threadIdx.x & 3;
  unsigned ow[8];
#pragma unroll
  for (int i = 0; i < 8; ++i)
    ow[i] = cvt_pk(tileT[nrow][kq * 16 + 2 * i], tileT[nrow][kq * 16 + 2 * i + 1]);
  u16* dst = wt + (size_t)(n0 + nrow) * K + k0 + kq * 16;
  *(uint4*)dst = *(uint4*)(ow);
  *(uint4*)(dst + 8) = *(uint4*)(ow + 4);
}

// ---------------- LayerNorm over C=1024, fp32 in -> bf16 out ----------------
__global__ __launch_bounds__(256) void k_ln(const float* __restrict__ x, const float* __restrict__ g,
                                            const float* __restrict__ b, u16* __restrict__ out) {
  int row = blockIdx.x, t = threadIdx.x;
  const float4 v = ((const float4*)(x + (size_t)row * 1024))[t];
  float s = v.x + v.y + v.z + v.w;
  float ss = v.x * v.x + v.y * v.y + v.z * v.z + v.w * v.w;
  for (int o = 32; o; o >>= 1) { s += __shfl_down(s, o); ss += __shfl_down(ss, o); }
  __shared__ float red[10];
  int w = t >> 6;
  if ((t & 63) == 0) { red[w] = s; red[4 + w] = ss; }
  __syncthreads();
  if (t == 0) {
    float S = red[0] + red[1] + red[2] + red[3];
    float SS = red[4] + red[5] + red[6] + red[7];
    float mean = S * (1.f / 1024.f);
    float var = SS * (1.f / 1024.f) - mean * mean;
    red[8] = mean; red[9] = rsqrtf(var + 1e-6f);
  }
  __syncthreads();
  float mean = red[8], rstd = red[9];
  float4 gg = ((const float4*)g)[t], bb = ((const float4*)b)[t];
  ushort4 o4;
  o4.x = f2bf((v.x - mean) * rstd * gg.x + bb.x);
  o4.y = f2bf((v.y - mean) * rstd * gg.y + bb.y);
  o4.z = f2bf((v.z - mean) * rstd * gg.z + bb.z);
  o4.w = f2bf((v.w - mean) * rstd * gg.w + bb.w);
  ((ushort4*)(out + (size_t)row * 1024))[t] = o4;
}

// ---------------- GEMM (wide-N): BM in {64,128}, BN=128, double-buffered ----------------
template <int MODE, int BM>
__global__ __launch_bounds__(256) void k_gemm(const u16* __restrict__ A, const u16* __restrict__ Bt,
                                              const float* __restrict__ bias, void* outv,
                                              u16* kfrag, u16* vfrag,
                                              int M, int N, int K, int kcol0, int vcol0, float scale) {
  constexpr int NT = (BM == 128) ? 4 : 2;
  __shared__ u16 aL[2][BM * 64];
  __shared__ u16 bL[2][128 * 64];
  const int lane = threadIdx.x & 63, w = threadIdx.x >> 6, t = threadIdx.x;
  const int wm = (BM == 128) ? (w >> 1) : 0;
  const int wn = (BM == 128) ? (w & 1) : w;
  const int m0 = blockIdx.y * BM, n0 = blockIdx.x * 128;

  f32x4 acc[4][NT];
#pragma unroll
  for (int i = 0; i < 4; ++i)
#pragma unroll
    for (int j = 0; j < NT; ++j) acc[i][j] = (f32x4){0.f, 0.f, 0.f, 0.f};

  auto stage = [&](int buf, int kt) {
    const int k0 = kt << 6;
#pragma unroll
    for (int c = t; c < BM * 8; c += 256) {
      int row = c >> 3, c16 = c & 7;
      int sw = (c16 * 16) ^ ((row & 7) << 4);
      gload16((const char*)(A + (size_t)(m0 + row) * K + k0) + sw, (char*)aL[buf] + c * 16);
    }
#pragma unroll
    for (int c = t; c < 1024; c += 256) {
      int row = c >> 3, c16 = c & 7;
      int sw = (c16 * 16) ^ ((row & 7) << 4);
      gload16((const char*)(Bt + (size_t)(n0 + row) * K + k0) + sw, (char*)bL[buf] + c * 16);
    }
  };

  const int nkt = K >> 6;
  stage(0, 0);
  __syncthreads();
  int cur = 0;
  for (int kt = 0; kt < nkt; ++kt) {
    if (kt + 1 < nkt) stage(cur ^ 1, kt + 1);
#pragma unroll
    for (int kk = 0; kk < 2; ++kk) {
      const int cb = kk * 64 + ((lane >> 4) << 4);
      bf16x8 af[4], bfr[NT];
#pragma unroll
      for (int mi = 0; mi < 4; ++mi) {
        int row = wm * 64 + mi * 16 + (lane & 15);
        af[mi] = *(const bf16x8*)((const char*)aL[cur] + row * 128 + (cb ^ ((row & 7) << 4)));
      }
#pragma unroll
      for (int ni = 0; ni < NT; ++ni) {
        int row = wn * (NT * 16) + ni * 16 + (lane & 15);
        bfr[ni] = *(const bf16x8*)((const char*)bL[cur] + row * 128 + (cb ^ ((row & 7) << 4)));
      }
#pragma unroll
      for (int mi = 0; mi < 4; ++mi)
#pragma unroll
        for (int ni = 0; ni < NT; ++ni)
          acc[mi][ni] = __builtin_amdgcn_mfma_f32_16x16x32_bf16(af[mi], bfr[ni], acc[mi][ni], 0, 0, 0);
    }
    __syncthreads();
    cur ^= 1;
  }

  const int cBase = n0 + wn * (NT * 16) + (lane & 15);
  const int rBase = m0 + wm * 64 + ((lane >> 4) << 2);
#pragma unroll
  for (int ni = 0; ni < NT; ++ni) {
    int col = cBase + ni * 16;
    float bv = bias[col];
#pragma unroll
    for (int mi = 0; mi < 4; ++mi) {
      int row = rBase + mi * 16;
      f32x4 a = acc[mi][ni];
      if (MODE == 0) {
        if (col >= vcol0) {
          int dv = col - vcol0;
          int hh = dv >> 6, dl = dv & 63, vh = dl >> 5, lov = dl & 31;
          int ktb = row >> 6, ksl = (row >> 4) & 3, hi2 = (row >> 3) & 1, e0 = row & 7;
          size_t idx = ((((size_t)(hh * 32 + ktb) * 2 + vh) * 4 + ksl) * 64 + hi2 * 32 + lov) * 8 + e0;
          ushort4 o4;
          o4.x = f2bf(a[0] + bv); o4.y = f2bf(a[1] + bv);
          o4.z = f2bf(a[2] + bv); o4.w = f2bf(a[3] + bv);
          *(ushort4*)(vfrag + idx) = o4;
        } else if (col >= kcol0) {
          int ck = col - kcol0;
          int hh = ck >> 6, d = ck & 63, sl = d >> 4, hi2 = (d >> 3) & 1, e = d & 7;
#pragma unroll
          for (int r = 0; r < 4; ++r) {
            int s = row + r;
            size_t idx = (((size_t)(hh * 64 + (s >> 5)) * 4 + sl) * 64 + hi2 * 32 + (s & 31)) * 8 + e;
            kfrag[idx] = f2bf(a[r] + bv);
          }
        } else {
#pragma unroll
          for (int r = 0; r < 4; ++r)
            ((u16*)outv)[(size_t)(row + r) * 1024 + col] = f2bf((a[r] + bv) * scale);
        }
      } else {
#pragma unroll
        for (int r = 0; r < 4; ++r) {
          float v = a[r] + bv;
          ((u16*)outv)[(size_t)(row + r) * N + col] =
              f2bf(0.5f * v * (1.f + erff(v * 0.70710678118654752f)));
        }
      }
    }
  }
}

// ---------------- GEMM (skinny-N): 2-way in-block split-K, BM=BN=64, 8 waves ----------------
template <int MODE>
__global__ __launch_bounds__(512, 2) void k_gemm_sk(const u16* __restrict__ A, const u16* __restrict__ Bt,
                                                    const float* __restrict__ bias, const float* res,
                                                    void* outv, int M, int N, int K, float scale) {
  __shared__ u16 aL[2][2][64 * 64];   // [half][buf]
  __shared__ u16 bL[2][2][64 * 64];
  const int t = threadIdx.x, lane = t & 63, w = t >> 6;
  const int kh = w >> 2, ws2 = w & 3;
  const int ts = t & 255;
  const int m0 = blockIdx.y * 64, n0 = blockIdx.x * 64;
  const int nktH = (K >> 6) >> 1;
  const int kbase = kh * nktH;

  f32x4 acc[4];
#pragma unroll
  for (int i = 0; i < 4; ++i) acc[i] = (f32x4){0.f, 0.f, 0.f, 0.f};

  auto stage = [&](int buf, int kt) {
    const int k0 = (kbase + kt) << 6;
#pragma unroll
    for (int i = 0; i < 2; ++i) {
      int c = i * 256 + ts;
      int row = c >> 3, c16 = c & 7;
      int sw = (c16 * 16) ^ ((row & 7) << 4);
      gload16((const char*)(A + (size_t)(m0 + row) * K + k0) + sw, (char*)aL[kh][buf] + c * 16);
      gload16((const char*)(Bt + (size_t)(n0 + row) * K + k0) + sw, (char*)bL[kh][buf] + c * 16);
    }
  };

  stage(0, 0);
  __syncthreads();
  int cur = 0;
  for (int kt = 0; kt < nktH; ++kt) {
    if (kt + 1 < nktH) stage(cur ^ 1, kt + 1);
#pragma unroll
    for (int kk = 0; kk < 2; ++kk) {
      const int cb = kk * 64 + ((lane >> 4) << 4);
      bf16x8 af[4], bfr;
#pragma unroll
      for (int mi = 0; mi < 4; ++mi) {
        int row = mi * 16 + (lane & 15);
        af[mi] = *(const bf16x8*)((const char*)aL[kh][cur] + row * 128 + (cb ^ ((row & 7) << 4)));
      }
      {
        int row = ws2 * 16 + (lane & 15);
        bfr = *(const bf16x8*)((const char*)bL[kh][cur] + row * 128 + (cb ^ ((row & 7) << 4)));
      }
#pragma unroll
      for (int mi = 0; mi < 4; ++mi)
        acc[mi] = __builtin_amdgcn_mfma_f32_16x16x32_bf16(af[mi], bfr, acc[mi], 0, 0, 0);
    }
    __syncthreads();
    cur ^= 1;
  }

  float* mergeF = (float*)aL;
  const int r0l = (lane >> 4) << 2, col16 = lane & 15;
  if (kh == 1) {
#pragma unroll
    for (int mi = 0; mi < 4; ++mi)
#pragma unroll
      for (int r = 0; r < 4; ++r)
        mergeF[(ws2 * 64 + mi * 16 + r0l + r) * 17 + col16] = acc[mi][r];
  }
  __syncthreads();
  if (kh == 0) {
    int col = n0 + ws2 * 16 + col16;
    float bv = bias[col];
#pragma unroll
    for (int mi = 0; mi < 4; ++mi) {
      int row = m0 + mi * 16 + r0l;
#pragma unroll
      for (int r = 0; r < 4; ++r) {
        float v = acc[mi][r] + mergeF[(ws2 * 64 + mi * 16 + r0l + r) * 17 + col16] + bv;
        size_t idx = (size_t)(row + r) * N + col;
        if (MODE == 0) ((u16*)outv)[idx] = f2bf(v * scale);
        else ((float*)outv)[idx] = res[idx] + v;
      }
    }
  }
}

// ---------------- flash attention: R17 structure + permlane32_swap P-pack (T12) -----------
template <bool CAUSAL>
__global__ __launch_bounds__(256, 4) void k_attn6(const u16* __restrict__ Q, const u16* __restrict__ KF,
                                                  const u16* __restrict__ VF, u16* __restrict__ O,
                                                  int S, int qstride) {
  __shared__ __align__(16) char smem[24 * 1024 + 1024];
  const int t = threadIdx.x, lane = t & 63, ks = t >> 6;  // split 0..3
  const int lo5 = lane & 31, hi = lane >> 5;
  const int h = blockIdx.x;
  const int bq = blockIdx.y;
  const int qt = (bq & 1) ? (63 - (bq >> 1)) : (bq >> 1); // causal light/heavy interleave
  const int hd0 = h * 64;
  const int q0 = qt * 32;

  bf16x8 qf[4];
#pragma unroll
  for (int sl = 0; sl < 4; ++sl)
    qf[sl] = *(const bf16x8*)(Q + (size_t)(q0 + lo5) * qstride + hd0 + sl * 16 + hi * 8);

  f32x16 oa0 = {}, oa1 = {};
  float mrun = -1e30f, lsum = 0.f;

  const int dtile = qt >> 1;                              // diagonal kv-tile index
  const int nkt = CAUSAL ? (dtile + 1) : (S >> 6);
  const u16* KFh = KF + (size_t)h * (S / 32) * 2048 + lane * 8;
  const u16* VFh = VF + (size_t)h * (S / 64) * 4096 + lane * 8;

  for (int kt = ks; kt < nkt; kt += 4) {
    const u16* Kt = KFh + (size_t)(2 * kt) * 2048;
    f32x16 s0 = {}, s1 = {};
#pragma unroll
    for (int sl = 0; sl < 4; ++sl) {
      bf16x8 kf0 = *(const bf16x8*)(Kt + sl * 512);
      bf16x8 kf1 = *(const bf16x8*)(Kt + 2048 + sl * 512);
      s0 = __builtin_amdgcn_mfma_f32_32x32x16_bf16(kf0, qf[sl], s0, 0, 0, 0);
      s1 = __builtin_amdgcn_mfma_f32_32x32x16_bf16(kf1, qf[sl], s1, 0, 0, 0);
    }
    if (CAUSAL && kt == dtile) {
      int qg = q0 + lo5;
#pragma unroll
      for (int r = 0; r < 16; ++r) {
        int kg = kt * 64 + (r & 3) + 8 * (r >> 2) + 4 * hi;
        if (kg > qg) s0[r] = -1e30f;
        if (kg + 32 > qg) s1[r] = -1e30f;
      }
    }
    float mx[16];
#pragma unroll
    for (int r = 0; r < 16; ++r) mx[r] = fmaxf(s0[r], s1[r]);
#pragma unroll
    for (int st = 8; st; st >>= 1)
#pragma unroll
      for (int r = 0; r < 8; ++r)
        if (r < st) mx[r] = fmaxf(mx[r], mx[r + st]);
    float pm = fmaxf(mx[0], __shfl_xor(mx[0], 32));

    if (!__all(pm - mrun <= 8.f)) {   // defer-max (T13)
      float mnew = fmaxf(mrun, pm);
      float sc = exp2f(mrun - mnew);
      lsum *= sc;
#pragma unroll
      for (int r = 0; r < 16; ++r) { oa0[r] *= sc; oa1[r] *= sc; }
      mrun = mnew;
    }

#pragma unroll
    for (int r = 0; r < 16; ++r) s0[r] = exp2f(s0[r] - mrun);
#pragma unroll
    for (int r = 0; r < 16; ++r) s1[r] = exp2f(s1[r] - mrun);
    float sm[16];
#pragma unroll
    for (int r = 0; r < 16; ++r) sm[r] = s0[r] + s1[r];
#pragma unroll
    for (int st = 8; st; st >>= 1)
#pragma unroll
      for (int r = 0; r < 8; ++r)
        if (r < st) sm[r] += sm[r + st];
    lsum += sm[0] + __shfl_xor(sm[0], 32);

    const u16* Vt = VFh + (size_t)kt * 4096;
#pragma unroll
    for (int ksl = 0; ksl < 4; ++ksl) {
      const int base = 8 * (ksl & 1);
      float pA0, pA1, pA2, pA3, pB0, pB1, pB2, pB3;
      if (ksl < 2) {
        pA0 = s0[base + 0]; pA1 = s0[base + 1]; pA2 = s0[base + 2]; pA3 = s0[base + 3];
        pB0 = s0[base + 4]; pB1 = s0[base + 5]; pB2 = s0[base + 6]; pB3 = s0[base + 7];
      } else {
        pA0 = s1[base + 0]; pA1 = s1[base + 1]; pA2 = s1[base + 2]; pA3 = s1[base + 3];
        pB0 = s1[base + 4]; pB1 = s1[base + 5]; pB2 = s1[base + 6]; pB3 = s1[base + 7];
      }
      unsigned a01 = cvt_pk(pA0, pA1), a23 = cvt_pk(pA2, pA3);
      unsigned b01 = cvt_pk(pB0, pB1), b23 = cvt_pk(pB2, pB3);
      // permlane32_swap: a := [a.lo | b.lo-from-lane-32], b := [a.hi-from-lane+32 | b.hi]
      // equals the previous (hi ? shfl_xor(.,32) : .) selects — 2 ops replace 4 shfl + 4 sel
      swap32(a01, b01);
      swap32(a23, b23);
      union { unsigned u[4]; bf16x8 v; } pf;
      pf.u[0] = a01;
      pf.u[1] = a23;
      pf.u[2] = b01;
      pf.u[3] = b23;
      bf16x8 vf0 = *(const bf16x8*)(Vt + ksl * 512);
      bf16x8 vf1 = *(const bf16x8*)(Vt + 2048 + ksl * 512);
      oa0 = __builtin_amdgcn_mfma_f32_32x32x16_bf16(vf0, pf.v, oa0, 0, 0, 0);
      oa1 = __builtin_amdgcn_mfma_f32_32x32x16_bf16(vf1, pf.v, oa1, 0, 0, 0);
    }
  }
  __syncthreads();

  // ---- merge across 4 splits (tree: {2,3}->{0,1}, then 1->0) ----
  float* mlBuf = (float*)(smem + 24576);
#define OB_BYTE(g, halfoff) (lo5 * 256 + (((halfoff) + 32 * (g) + 16 * hi) ^ ((lo5 & 15) << 4)))
  if (ks >= 2) {
    char* ob = smem + (ks - 2) * 8192;
#pragma unroll
    for (int g = 0; g < 4; ++g) {
      *(float4*)(ob + OB_BYTE(g, 0)) = make_float4(oa0[4 * g + 0], oa0[4 * g + 1], oa0[4 * g + 2], oa0[4 * g + 3]);
      *(float4*)(ob + OB_BYTE(g, 128)) = make_float4(oa1[4 * g + 0], oa1[4 * g + 1], oa1[4 * g + 2], oa1[4 * g + 3]);
    }
    if (hi == 0) { mlBuf[(ks * 32 + lo5) * 2] = mrun; mlBuf[(ks * 32 + lo5) * 2 + 1] = lsum; }
  }
  __syncthreads();
  if (ks < 2) {
    int pw = ks + 2;
    char* ob = smem + ks * 8192;
    float mB = mlBuf[(pw * 32 + lo5) * 2], lB = mlBuf[(pw * 32 + lo5) * 2 + 1];
    float M = fmaxf(mrun, mB);
    float sA = exp2f(mrun - M), sB = exp2f(mB - M);
    lsum = lsum * sA + lB * sB;
    mrun = M;
#pragma unroll
    for (int g = 0; g < 4; ++g) {
      float4 v0 = *(const float4*)(ob + OB_BYTE(g, 0));
      float4 v1 = *(const float4*)(ob + OB_BYTE(g, 128));
      oa0[4 * g + 0] = oa0[4 * g + 0] * sA + v0.x * sB;
      oa0[4 * g + 1] = oa0[4 * g + 1] * sA + v0.y * sB;
      oa0[4 * g + 2] = oa0[4 * g + 2] * sA + v0.z * sB;
      oa0[4 * g + 3] = oa0[4 * g + 3] * sA + v0.w * sB;
      oa1[4 * g + 0] = oa1[4 * g + 0] * sA + v1.x * sB;
      oa1[4 * g + 1] = oa1[4 * g + 1] * sA + v1.y * sB;
      oa1[4 * g + 2] = oa1[4 * g + 2] * sA + v1.z * sB;
      oa1[4 * g + 3] = oa1[4 * g + 3] * sA + v1.w * sB;
    }
  }
  if (ks == 1) {
    char* ob = smem + 16384;
#pragma unroll
    for (int g = 0; g < 4; ++g) {
      *(float4*)(ob + OB_BYTE(g, 0)) = make_float4(oa0[4 * g + 0], oa0[4 * g + 1], oa0[4 * g + 2], oa0[4 * g + 3]);
      *(float4*)(ob + OB_BYTE(g, 128)) = make_float4(oa1[4 * g + 0], oa1[4 * g + 1], oa1[4 * g + 2], oa1[4 * g + 3]);
    }
    if (hi == 0) { mlBuf[(32 + lo5) * 2] = mrun; mlBuf[(32 + lo5) * 2 + 1] = lsum; }
  }
  __syncthreads();
  if (ks == 0) {
    char* ob = smem + 16384;
    float mB = mlBuf[(32 + lo5) * 2], lB = mlBuf[(32 + lo5) * 2 + 1];
    float M = fmaxf(mrun, mB);
    float sA = exp2f(mrun - M), sB = exp2f(mB - M);
    lsum = lsum * sA + lB * sB;
#pragma unroll
    for (int g = 0; g < 4; ++g) {
      float4 v0 = *(const float4*)(ob + OB_BYTE(g, 0));
      float4 v1 = *(const float4*)(ob + OB_BYTE(g, 128));
      oa0[4 * g + 0] = oa0[4 * g + 0] * sA + v0.x * sB;
      oa0[4 * g + 1] = oa0[4 * g + 1] * sA + v0.y * sB;
      oa0[4 * g + 2] = oa0[4 * g + 2] * sA + v0.z * sB;
      oa0[4 * g + 3] = oa0[4 * g + 3] * sA + v0.w * sB;
      oa1[4 * g + 0] = oa1[4 * g + 0] * sA + v1.x * sB;
      oa1[4 * g + 1] = oa1[4 * g + 1] * sA + v1.y * sB;
      oa1[4 * g + 2] = oa1[4 * g + 2] * sA + v1.z * sB;
      oa1[4 * g + 3] = oa1[4 * g + 3] * sA + v1.w * sB;
    }
    // ldsO (4KB) aliases ob buffer 0: last read of buffer 0 was before barrier above
    float inv = 1.f / lsum;
    u16* ldsO = (u16*)smem;
    int qrow = lo5;
#pragma unroll
    for (int g = 0; g < 4; ++g) {
      unsigned w0 = cvt_pk(oa0[4 * g + 0] * inv, oa0[4 * g + 1] * inv);
      unsigned w1 = cvt_pk(oa0[4 * g + 2] * inv, oa0[4 * g + 3] * inv);
      int dby = (8 * g + 4 * hi) * 2;
      *(uint2*)((char*)ldsO + qrow * 128 + (dby ^ ((qrow & 7) << 4))) = make_uint2(w0, w1);
      unsigned w2 = cvt_pk(oa1[4 * g + 0] * inv, oa1[4 * g + 1] * inv);
      unsigned w3 = cvt_pk(oa1[4 * g + 2] * inv, oa1[4 * g + 3] * inv);
      int dby2 = (32 + 8 * g + 4 * hi) * 2;
      *(uint2*)((char*)ldsO + qrow * 128 + (dby2 ^ ((qrow & 7) << 4))) = make_uint2(w2, w3);
    }
  }
  __syncthreads();
  {
    u16* ldsO = (u16*)smem;
    int row = t >> 3, c16 = t & 7;   // 256 thr = 32 rows x 8 chunks of 16B
    uint4 val = *(const uint4*)((const char*)ldsO + row * 128 + ((c16 * 16) ^ ((row & 7) << 4)));
    *(uint4*)(O + (size_t)(q0 + row) * 1024 + hd0 + c16 * 8) = val;
  }
#undef OB_BYTE
}

// ==========================================================================================
extern "C" void kernel_launch(void* const* d_in, const int* in_sizes, int n_in,
                              void* d_out, int out_size, void* d_ws, size_t ws_size,
                              hipStream_t stream) {
  const float* features = (const float*)d_in[0];
  const float* enc      = (const float*)d_in[1];
  const float* g1a = (const float*)d_in[2];  const float* b1a = (const float*)d_in[3];
  const float* g1b = (const float*)d_in[4];  const float* b1b = (const float*)d_in[5];
  const float* g2a = (const float*)d_in[6];  const float* b2a = (const float*)d_in[7];
  const float* g2b = (const float*)d_in[8];  const float* b2b = (const float*)d_in[9];
  const float* sa_qw = (const float*)d_in[10]; const float* sa_qb = (const float*)d_in[11];
  const float* sa_kw = (const float*)d_in[12]; const float* sa_kb = (const float*)d_in[13];
  const float* sa_vw = (const float*)d_in[14]; const float* sa_vb = (const float*)d_in[15];
  const float* sa_pw = (const float*)d_in[16]; const float* sa_pb = (const float*)d_in[17];
  const float* ca_qw = (const float*)d_in[18]; const float* ca_qb = (const float*)d_in[19];
  const float* ca_kw = (const float*)d_in[20]; const float* ca_kb = (const float*)d_in[21];
  const float* ca_vw = (const float*)d_in[22]; const float* ca_vb = (const float*)d_in[23];
  const float* ca_pw = (const float*)d_in[24]; const float* ca_pb = (const float*)d_in[25];
  const float* m1_w1 = (const float*)d_in[26]; const float* m1_b1 = (const float*)d_in[27];
  const float* m1_w2 = (const float*)d_in[28]; const float* m1_b2 = (const float*)d_in[29];
  const float* m2_w1 = (const float*)d_in[30]; const float* m2_b1 = (const float*)d_in[31];
  const float* m2_w2 = (const float*)d_in[32]; const float* m2_b2 = (const float*)d_in[33];

  const int S = 2048, C = 1024, Mh = 4096;
  const size_t CC = (size_t)C * C;
  float* xout = (float*)d_out;

  char* p = (char*)d_ws;
  auto take = [&](size_t bytes) { char* q = p; p += (bytes + 255) & ~(size_t)255; return q; };
  u16* wt_qkv  = (u16*)take(3 * CC * 2);
  u16* wt_sap  = (u16*)take(CC * 2);
  u16* wt_cap  = (u16*)take(CC * 2);
  u16* wt_caq  = (u16*)take(CC * 2);
  u16* wt_ckv  = (u16*)take(2 * CC * 2);
  u16* wt_m1w1 = (u16*)take((size_t)C * Mh * 2);
  u16* wt_m1w2 = (u16*)take((size_t)C * Mh * 2);
  u16* wt_m2w1 = (u16*)take((size_t)C * Mh * 2);
  u16* wt_m2w2 = (u16*)take((size_t)C * Mh * 2);
  float* bias_qkv = (float*)take(3 * C * 4);
  float* bias_ckv = (float*)take(2 * C * 4);
  u16* xn   = (u16*)take((size_t)S * C * 2);
  u16* encb = (u16*)take((size_t)S * C * 2);
  u16* abuf = (u16*)take((size_t)S * C * 2);
  u16* hbuf = (u16*)take((size_t)S * Mh * 2);
  u16* qsbuf = hbuf;
  u16* kf_b  = hbuf + (size_t)2 * 1024 * 1024;
  u16* vf_b  = hbuf + (size_t)4 * 1024 * 1024;

  dim3 blk(256);
  const float qs2 = 0.125f * 1.4426950408889634f;  // hd^-0.5 * log2(e)

  TransArgs ta;
  ta.src[0] = sa_qw;  ta.dst[0] = wt_qkv;
  ta.src[1] = sa_kw;  ta.dst[1] = wt_qkv + CC;
  ta.src[2] = sa_vw;  ta.dst[2] = wt_qkv + 2 * CC;
  ta.src[3] = sa_pw;  ta.dst[3] = wt_sap;
  ta.src[4] = ca_pw;  ta.dst[4] = wt_cap;
  ta.src[5] = ca_qw;  ta.dst[5] = wt_caq;
  ta.src[6] = ca_kw;  ta.dst[6] = wt_ckv;
  ta.src[7] = ca_vw;  ta.dst[7] = wt_ckv + CC;
  ta.src[8] = m1_w1;  ta.dst[8] = wt_m1w1;
  ta.src[9] = m1_w2;  ta.dst[9] = wt_m1w2;
  ta.src[10] = m2_w1; ta.dst[10] = wt_m2w1;
  ta.src[11] = m2_w2; ta.dst[11] = wt_m2w2;
  ta.enc = enc; ta.encb = encb;
  ta.bq = bias_qkv; ta.bc = bias_ckv;
  ta.qb = sa_qb; ta.kb = sa_kb; ta.vb = sa_vb; ta.ckb = ca_kb; ta.cvb = ca_vb;
  k_prepass<<<dim3(8212), blk, 0, stream>>>(ta);

  // --- block 1: self-attention (causal)
  k_ln<<<S, blk, 0, stream>>>(features, g1a, b1a, xn);
  k_gemm<0, 128><<<dim3(24, 16), blk, 0, stream>>>(xn, wt_qkv, bias_qkv, qsbuf, kf_b, vf_b,
                                                   S, 3072, C, 1024, 2048, qs2);
  k_attn6<true><<<dim3(16, 64), blk, 0, stream>>>(qsbuf, kf_b, vf_b, abuf, S, 1024);
  k_gemm_sk<1><<<dim3(16, 32), dim3(512), 0, stream>>>(abuf, wt_sap, sa_pb, features, xout, S, C, C, 1.f);
  // --- MLP 1
  k_ln<<<S, blk, 0, stream>>>(xout, g1b, b1b, xn);
  k_gemm<2, 128><<<dim3(32, 16), blk, 0, stream>>>(xn, wt_m1w1, m1_b1, hbuf, nullptr, nullptr,
                                                   S, Mh, C, 0, 1 << 30, 1.f);
  k_gemm_sk<1><<<dim3(16, 32), dim3(512), 0, stream>>>(hbuf, wt_m1w2, m1_b2, xout, xout, S, C, Mh, 1.f);
  // --- block 2: cross-attention
  k_ln<<<S, blk, 0, stream>>>(xout, g2a, b2a, xn);
  k_gemm_sk<0><<<dim3(16, 32), dim3(512), 0, stream>>>(xn, wt_caq, ca_qb, nullptr, qsbuf, S, C, C, qs2);
  k_gemm<0, 64><<<dim3(16, 32), blk, 0, stream>>>(encb, wt_ckv, bias_ckv, nullptr, kf_b, vf_b,
                                                  S, 2048, C, 0, 1024, 1.f);
  k_attn6<false><<<dim3(16, 64), blk, 0, stream>>>(qsbuf, kf_b, vf_b, abuf, S, 1024);
  k_gemm_sk<1><<<dim3(16, 32), dim3(512), 0, stream>>>(abuf, wt_cap, ca_pb, xout, xout, S, C, C, 1.f);
  // --- MLP 2
  k_ln<<<S, blk, 0, stream>>>(xout, g2b, b2b, xn);
  k_gemm<2, 128><<<dim3(32, 16), blk, 0, stream>>>(xn, wt_m2w1, m2_b1, hbuf, nullptr, nullptr,
                                                   S, Mh, C, 0, 1 << 30, 1.f);
  k_gemm_sk<1><<<dim3(16, 32), dim3(512), 0, stream>>>(hbuf, wt_m2w2, m2_b2, xout, xout, S, C, Mh, 1.f);
}

// Round 20
// 312.761 us; speedup vs baseline: 1.0175x; 1.0175x over previous
//
#include <hip/hip_runtime.h>
#include <math.h>

typedef unsigned short u16;
typedef __bf16 bf16_t;
typedef bf16_t bf16x8 __attribute__((ext_vector_type(8)));
typedef float f32x4 __attribute__((ext_vector_type(4)));
typedef float f32x16 __attribute__((ext_vector_type(16)));

#define DI __device__ __forceinline__

DI u16 f2bf(float f) {
  union { float f; unsigned u; } c; c.f = f;
  unsigned r = c.u + 0x7FFFu + ((c.u >> 16) & 1u);
  return (u16)(r >> 16);
}

DI unsigned cvt_pk(float lo, float hi_) {  // dst[15:0]=bf16(lo), dst[31:16]=bf16(hi_)
  unsigned d;
  asm("v_cvt_pk_bf16_f32 %0, %1, %2" : "=v"(d) : "v"(lo), "v"(hi_));
  return d;
}

typedef __attribute__((address_space(1))) void* gas_ptr;
typedef __attribute__((address_space(3))) void* las_ptr;

DI void gload16(const void* g, void* l) {
  __builtin_amdgcn_global_load_lds((gas_ptr)g, (las_ptr)l, 16, 0, 0);
}

// ------- fused pre-pass: 12 weight transposes + enc cvt + biaspack + LN1a in ONE launch ---
// blocks [0,6144): transpose; [6144,8192): enc cvt; [8192,8212): biaspack;
// [8212,10260): LN1a rows (features -> xn), which depends only on kernel inputs.
struct TransArgs {
  const float* src[12]; u16* dst[12];
  const float* enc; u16* encb;
  float* bq; float* bc;
  const float* qb; const float* kb; const float* vb; const float* ckb; const float* cvb;
  const float* feat; const float* g1a; const float* b1a; u16* xn;
};
__global__ __launch_bounds__(256) void k_prepass(TransArgs ta) {
  int bx = blockIdx.x;
  int t = threadIdx.x;
  if (bx >= 8212) {                   // ---- LN1a: row = bx-8212, features -> xn ----
    __shared__ float red[10];
    int row = bx - 8212;
    const float4 v = ((const float4*)(ta.feat + (size_t)row * 1024))[t];
    float s = v.x + v.y + v.z + v.w;
    float ss = v.x * v.x + v.y * v.y + v.z * v.z + v.w * v.w;
    for (int o = 32; o; o >>= 1) { s += __shfl_down(s, o); ss += __shfl_down(ss, o); }
    int w = t >> 6;
    if ((t & 63) == 0) { red[w] = s; red[4 + w] = ss; }
    __syncthreads();
    if (t == 0) {
      float S = red[0] + red[1] + red[2] + red[3];
      float SS = red[4] + red[5] + red[6] + red[7];
      float mean = S * (1.f / 1024.f);
      float var = SS * (1.f / 1024.f) - mean * mean;
      red[8] = mean; red[9] = rsqrtf(var + 1e-6f);
    }
    __syncthreads();
    float mean = red[8], rstd = red[9];
    float4 gg = ((const float4*)ta.g1a)[t], bb = ((const float4*)ta.b1a)[t];
    ushort4 o4;
    o4.x = f2bf((v.x - mean) * rstd * gg.x + bb.x);
    o4.y = f2bf((v.y - mean) * rstd * gg.y + bb.y);
    o4.z = f2bf((v.z - mean) * rstd * gg.z + bb.z);
    o4.w = f2bf((v.w - mean) * rstd * gg.w + bb.w);
    ((ushort4*)(ta.xn + (size_t)row * 1024))[t] = o4;
    return;
  }
  if (bx >= 8192) {                   // ---- biaspack (20 blocks) ----
    int i = (bx - 8192) * 256 + t;
    if (i < 1024) ta.bq[i] = ta.qb[i];
    else if (i < 2048) ta.bq[i] = ta.kb[i - 1024];
    else if (i < 3072) ta.bq[i] = ta.vb[i - 2048];
    else if (i < 4096) ta.bc[i - 3072] = ta.ckb[i - 3072];
    else if (i < 5120) ta.bc[i - 3072] = ta.cvb[i - 4096];
    return;
  }
  if (bx >= 6144) {                   // ---- enc cvt ----
    int i = (bx - 6144) * 256 + t;
    float4 v = ((const float4*)ta.enc)[i];
    ushort4 o;
    o.x = f2bf(v.x); o.y = f2bf(v.y); o.z = f2bf(v.z); o.w = f2bf(v.w);
    ((ushort4*)ta.encb)[i] = o;
    return;
  }
  // ---- transpose: w [K][N] f32 -> wt [N][K] bf16, 64x64 tiles ----
  __shared__ float tileT[64][65];
  int z, local, K, N;
  if (bx < 2048) { z = bx >> 8; local = bx & 255; K = 1024; N = 1024; }
  else {
    int i = bx - 2048; z = 8 + (i >> 10); local = i & 1023;
    if (z & 1) { K = 4096; N = 1024; } else { K = 1024; N = 4096; }
  }
  const float* w = ta.src[z];
  u16* wt = ta.dst[z];
  const int nT = N >> 6;
  const int n0 = (local % nT) * 64, k0 = (local / nT) * 64;

  const int krow = t >> 4, c4 = t & 15;
#pragma unroll
  for (int i = 0; i < 4; ++i) {
    int kr = krow + i * 16;
    float4 v = *(const float4*)(w + (size_t)(k0 + kr) * N + n0 + c4 * 4);
    tileT[c4 * 4 + 0][kr] = v.x;
    tileT[c4 * 4 + 1][kr] = v.y;
    tileT[c4 * 4 + 2][kr] = v.z;
    tileT[c4 * 4 + 3][kr] = v.w;
  }
  __syncthreads();
  const int nrow = t >> 2, kq = t & 3;
  unsigned ow[8];
#pragma unroll
  for (int i = 0; i < 8; ++i)
    ow[i] = cvt_pk(tileT[nrow][kq * 16 + 2 * i], tileT[nrow][kq * 16 + 2 * i + 1]);
  u16* dst = wt + (size_t)(n0 + nrow) * K + k0 + kq * 16;
  *(uint4*)dst = *(uint4*)(ow);
  *(uint4*)(dst + 8) = *(uint4*)(ow + 4);
}

// ---------------- LayerNorm over C=1024, fp32 in -> bf16 out ----------------
__global__ __launch_bounds__(256) void k_ln(const float* __restrict__ x, const float* __restrict__ g,
                                            const float* __restrict__ b, u16* __restrict__ out) {
  int row = blockIdx.x, t = threadIdx.x;
  const float4 v = ((const float4*)(x + (size_t)row * 1024))[t];
  float s = v.x + v.y + v.z + v.w;
  float ss = v.x * v.x + v.y * v.y + v.z * v.z + v.w * v.w;
  for (int o = 32; o; o >>= 1) { s += __shfl_down(s, o); ss += __shfl_down(ss, o); }
  __shared__ float red[10];
  int w = t >> 6;
  if ((t & 63) == 0) { red[w] = s; red[4 + w] = ss; }
  __syncthreads();
  if (t == 0) {
    float S = red[0] + red[1] + red[2] + red[3];
    float SS = red[4] + red[5] + red[6] + red[7];
    float mean = S * (1.f / 1024.f);
    float var = SS * (1.f / 1024.f) - mean * mean;
    red[8] = mean; red[9] = rsqrtf(var + 1e-6f);
  }
  __syncthreads();
  float mean = red[8], rstd = red[9];
  float4 gg = ((const float4*)g)[t], bb = ((const float4*)b)[t];
  ushort4 o4;
  o4.x = f2bf((v.x - mean) * rstd * gg.x + bb.x);
  o4.y = f2bf((v.y - mean) * rstd * gg.y + bb.y);
  o4.z = f2bf((v.z - mean) * rstd * gg.z + bb.z);
  o4.w = f2bf((v.w - mean) * rstd * gg.w + bb.w);
  ((ushort4*)(out + (size_t)row * 1024))[t] = o4;
}

// ---------------- GEMM (wide-N): BM in {64,128}, BN=128, double-buffered ----------------
// MODE 0: col<kcol0 -> Q bf16 [S][1024]*scale; kcol0<=col<vcol0 -> kfrag; col>=vcol0 -> vfrag.
// MODE 2: bf16 out = gelu(acc + bias), row-major stride N.
template <int MODE, int BM>
__global__ __launch_bounds__(256) void k_gemm(const u16* __restrict__ A, const u16* __restrict__ Bt,
                                              const float* __restrict__ bias, void* outv,
                                              u16* kfrag, u16* vfrag,
                                              int M, int N, int K, int kcol0, int vcol0, float scale) {
  constexpr int NT = (BM == 128) ? 4 : 2;
  __shared__ u16 aL[2][BM * 64];
  __shared__ u16 bL[2][128 * 64];
  const int lane = threadIdx.x & 63, w = threadIdx.x >> 6, t = threadIdx.x;
  const int wm = (BM == 128) ? (w >> 1) : 0;
  const int wn = (BM == 128) ? (w & 1) : w;
  const int m0 = blockIdx.y * BM, n0 = blockIdx.x * 128;

  f32x4 acc[4][NT];
#pragma unroll
  for (int i = 0; i < 4; ++i)
#pragma unroll
    for (int j = 0; j < NT; ++j) acc[i][j] = (f32x4){0.f, 0.f, 0.f, 0.f};

  auto stage = [&](int buf, int kt) {
    const int k0 = kt << 6;
#pragma unroll
    for (int c = t; c < BM * 8; c += 256) {
      int row = c >> 3, c16 = c & 7;
      int sw = (c16 * 16) ^ ((row & 7) << 4);
      gload16((const char*)(A + (size_t)(m0 + row) * K + k0) + sw, (char*)aL[buf] + c * 16);
    }
#pragma unroll
    for (int c = t; c < 1024; c += 256) {
      int row = c >> 3, c16 = c & 7;
      int sw = (c16 * 16) ^ ((row & 7) << 4);
      gload16((const char*)(Bt + (size_t)(n0 + row) * K + k0) + sw, (char*)bL[buf] + c * 16);
    }
  };

  const int nkt = K >> 6;
  stage(0, 0);
  __syncthreads();
  int cur = 0;
  for (int kt = 0; kt < nkt; ++kt) {
    if (kt + 1 < nkt) stage(cur ^ 1, kt + 1);
#pragma unroll
    for (int kk = 0; kk < 2; ++kk) {
      const int cb = kk * 64 + ((lane >> 4) << 4);
      bf16x8 af[4], bfr[NT];
#pragma unroll
      for (int mi = 0; mi < 4; ++mi) {
        int row = wm * 64 + mi * 16 + (lane & 15);
        af[mi] = *(const bf16x8*)((const char*)aL[cur] + row * 128 + (cb ^ ((row & 7) << 4)));
      }
#pragma unroll
      for (int ni = 0; ni < NT; ++ni) {
        int row = wn * (NT * 16) + ni * 16 + (lane & 15);
        bfr[ni] = *(const bf16x8*)((const char*)bL[cur] + row * 128 + (cb ^ ((row & 7) << 4)));
      }
#pragma unroll
      for (int mi = 0; mi < 4; ++mi)
#pragma unroll
        for (int ni = 0; ni < NT; ++ni)
          acc[mi][ni] = __builtin_amdgcn_mfma_f32_16x16x32_bf16(af[mi], bfr[ni], acc[mi][ni], 0, 0, 0);
    }
    __syncthreads();
    cur ^= 1;
  }

  const int cBase = n0 + wn * (NT * 16) + (lane & 15);
  const int rBase = m0 + wm * 64 + ((lane >> 4) << 2);
#pragma unroll
  for (int ni = 0; ni < NT; ++ni) {
    int col = cBase + ni * 16;
    float bv = bias[col];
#pragma unroll
    for (int mi = 0; mi < 4; ++mi) {
      int row = rBase + mi * 16;
      f32x4 a = acc[mi][ni];
      if (MODE == 0) {
        if (col >= vcol0) {
          int dv = col - vcol0;
          int hh = dv >> 6, dl = dv & 63, vh = dl >> 5, lov = dl & 31;
          int ktb = row >> 6, ksl = (row >> 4) & 3, hi2 = (row >> 3) & 1, e0 = row & 7;
          size_t idx = ((((size_t)(hh * 32 + ktb) * 2 + vh) * 4 + ksl) * 64 + hi2 * 32 + lov) * 8 + e0;
          ushort4 o4;
          o4.x = f2bf(a[0] + bv); o4.y = f2bf(a[1] + bv);
          o4.z = f2bf(a[2] + bv); o4.w = f2bf(a[3] + bv);
          *(ushort4*)(vfrag + idx) = o4;
        } else if (col >= kcol0) {
          int ck = col - kcol0;
          int hh = ck >> 6, d = ck & 63, sl = d >> 4, hi2 = (d >> 3) & 1, e = d & 7;
#pragma unroll
          for (int r = 0; r < 4; ++r) {
            int s = row + r;
            size_t idx = (((size_t)(hh * 64 + (s >> 5)) * 4 + sl) * 64 + hi2 * 32 + (s & 31)) * 8 + e;
            kfrag[idx] = f2bf(a[r] + bv);
          }
        } else {
#pragma unroll
          for (int r = 0; r < 4; ++r)
            ((u16*)outv)[(size_t)(row + r) * 1024 + col] = f2bf((a[r] + bv) * scale);
        }
      } else {
#pragma unroll
        for (int r = 0; r < 4; ++r) {
          float v = a[r] + bv;
          ((u16*)outv)[(size_t)(row + r) * N + col] =
              f2bf(0.5f * v * (1.f + erff(v * 0.70710678118654752f)));
        }
      }
    }
  }
}

// ---------------- GEMM (skinny-N): 2-way in-block split-K, BM=BN=64, 8 waves ----------------
template <int MODE>
__global__ __launch_bounds__(512, 2) void k_gemm_sk(const u16* __restrict__ A, const u16* __restrict__ Bt,
                                                    const float* __restrict__ bias, const float* res,
                                                    void* outv, int M, int N, int K, float scale) {
  __shared__ u16 aL[2][2][64 * 64];   // [half][buf]
  __shared__ u16 bL[2][2][64 * 64];
  const int t = threadIdx.x, lane = t & 63, w = t >> 6;
  const int kh = w >> 2, ws2 = w & 3;
  const int ts = t & 255;
  const int m0 = blockIdx.y * 64, n0 = blockIdx.x * 64;
  const int nktH = (K >> 6) >> 1;
  const int kbase = kh * nktH;

  f32x4 acc[4];
#pragma unroll
  for (int i = 0; i < 4; ++i) acc[i] = (f32x4){0.f, 0.f, 0.f, 0.f};

  auto stage = [&](int buf, int kt) {
    const int k0 = (kbase + kt) << 6;
#pragma unroll
    for (int i = 0; i < 2; ++i) {
      int c = i * 256 + ts;
      int row = c >> 3, c16 = c & 7;
      int sw = (c16 * 16) ^ ((row & 7) << 4);
      gload16((const char*)(A + (size_t)(m0 + row) * K + k0) + sw, (char*)aL[kh][buf] + c * 16);
      gload16((const char*)(Bt + (size_t)(n0 + row) * K + k0) + sw, (char*)bL[kh][buf] + c * 16);
    }
  };

  stage(0, 0);
  __syncthreads();
  int cur = 0;
  for (int kt = 0; kt < nktH; ++kt) {
    if (kt + 1 < nktH) stage(cur ^ 1, kt + 1);
#pragma unroll
    for (int kk = 0; kk < 2; ++kk) {
      const int cb = kk * 64 + ((lane >> 4) << 4);
      bf16x8 af[4], bfr;
#pragma unroll
      for (int mi = 0; mi < 4; ++mi) {
        int row = mi * 16 + (lane & 15);
        af[mi] = *(const bf16x8*)((const char*)aL[kh][cur] + row * 128 + (cb ^ ((row & 7) << 4)));
      }
      {
        int row = ws2 * 16 + (lane & 15);
        bfr = *(const bf16x8*)((const char*)bL[kh][cur] + row * 128 + (cb ^ ((row & 7) << 4)));
      }
#pragma unroll
      for (int mi = 0; mi < 4; ++mi)
        acc[mi] = __builtin_amdgcn_mfma_f32_16x16x32_bf16(af[mi], bfr, acc[mi], 0, 0, 0);
    }
    __syncthreads();
    cur ^= 1;
  }

  float* mergeF = (float*)aL;
  const int r0l = (lane >> 4) << 2, col16 = lane & 15;
  if (kh == 1) {
#pragma unroll
    for (int mi = 0; mi < 4; ++mi)
#pragma unroll
      for (int r = 0; r < 4; ++r)
        mergeF[(ws2 * 64 + mi * 16 + r0l + r) * 17 + col16] = acc[mi][r];
  }
  __syncthreads();
  if (kh == 0) {
    int col = n0 + ws2 * 16 + col16;
    float bv = bias[col];
#pragma unroll
    for (int mi = 0; mi < 4; ++mi) {
      int row = m0 + mi * 16 + r0l;
#pragma unroll
      for (int r = 0; r < 4; ++r) {
        float v = acc[mi][r] + mergeF[(ws2 * 64 + mi * 16 + r0l + r) * 17 + col16] + bv;
        size_t idx = (size_t)(row + r) * N + col;
        if (MODE == 0) ((u16*)outv)[idx] = f2bf(v * scale);
        else ((float*)outv)[idx] = res[idx] + v;
      }
    }
  }
}

// ---------------- flash attention: 256-thr blocks (1 q-wave x 4 splits), 4 blocks/CU -------
// R17/R14 form (best measured). Grid: (16 heads, 64 q-tiles of 32 rows). LDS 25KB.
template <bool CAUSAL>
__global__ __launch_bounds__(256, 4) void k_attn6(const u16* __restrict__ Q, const u16* __restrict__ KF,
                                                  const u16* __restrict__ VF, u16* __restrict__ O,
                                                  int S, int qstride) {
  __shared__ __align__(16) char smem[24 * 1024 + 1024];
  const int t = threadIdx.x, lane = t & 63, ks = t >> 6;  // split 0..3
  const int lo5 = lane & 31, hi = lane >> 5;
  const int h = blockIdx.x;
  const int bq = blockIdx.y;
  const int qt = (bq & 1) ? (63 - (bq >> 1)) : (bq >> 1); // causal light/heavy interleave
  const int hd0 = h * 64;
  const int q0 = qt * 32;

  bf16x8 qf[4];
#pragma unroll
  for (int sl = 0; sl < 4; ++sl)
    qf[sl] = *(const bf16x8*)(Q + (size_t)(q0 + lo5) * qstride + hd0 + sl * 16 + hi * 8);

  f32x16 oa0 = {}, oa1 = {};
  float mrun = -1e30f, lsum = 0.f;

  const int dtile = qt >> 1;                              // diagonal kv-tile index
  const int nkt = CAUSAL ? (dtile + 1) : (S >> 6);
  const u16* KFh = KF + (size_t)h * (S / 32) * 2048 + lane * 8;
  const u16* VFh = VF + (size_t)h * (S / 64) * 4096 + lane * 8;

  for (int kt = ks; kt < nkt; kt += 4) {
    const u16* Kt = KFh + (size_t)(2 * kt) * 2048;
    f32x16 s0 = {}, s1 = {};
#pragma unroll
    for (int sl = 0; sl < 4; ++sl) {
      bf16x8 kf0 = *(const bf16x8*)(Kt + sl * 512);
      bf16x8 kf1 = *(const bf16x8*)(Kt + 2048 + sl * 512);
      s0 = __builtin_amdgcn_mfma_f32_32x32x16_bf16(kf0, qf[sl], s0, 0, 0, 0);
      s1 = __builtin_amdgcn_mfma_f32_32x32x16_bf16(kf1, qf[sl], s1, 0, 0, 0);
    }
    if (CAUSAL && kt == dtile) {
      int qg = q0 + lo5;
#pragma unroll
      for (int r = 0; r < 16; ++r) {
        int kg = kt * 64 + (r & 3) + 8 * (r >> 2) + 4 * hi;
        if (kg > qg) s0[r] = -1e30f;
        if (kg + 32 > qg) s1[r] = -1e30f;
      }
    }
    float mx[16];
#pragma unroll
    for (int r = 0; r < 16; ++r) mx[r] = fmaxf(s0[r], s1[r]);
#pragma unroll
    for (int st = 8; st; st >>= 1)
#pragma unroll
      for (int r = 0; r < 8; ++r)
        if (r < st) mx[r] = fmaxf(mx[r], mx[r + st]);
    float pm = fmaxf(mx[0], __shfl_xor(mx[0], 32));

    if (!__all(pm - mrun <= 8.f)) {   // defer-max (T13)
      float mnew = fmaxf(mrun, pm);
      float sc = exp2f(mrun - mnew);
      lsum *= sc;
#pragma unroll
      for (int r = 0; r < 16; ++r) { oa0[r] *= sc; oa1[r] *= sc; }
      mrun = mnew;
    }

#pragma unroll
    for (int r = 0; r < 16; ++r) s0[r] = exp2f(s0[r] - mrun);
#pragma unroll
    for (int r = 0; r < 16; ++r) s1[r] = exp2f(s1[r] - mrun);
    float sm[16];
#pragma unroll
    for (int r = 0; r < 16; ++r) sm[r] = s0[r] + s1[r];
#pragma unroll
    for (int st = 8; st; st >>= 1)
#pragma unroll
      for (int r = 0; r < 8; ++r)
        if (r < st) sm[r] += sm[r + st];
    lsum += sm[0] + __shfl_xor(sm[0], 32);

    const u16* Vt = VFh + (size_t)kt * 4096;
#pragma unroll
    for (int ksl = 0; ksl < 4; ++ksl) {
      const int base = 8 * (ksl & 1);
      float pA0, pA1, pA2, pA3, pB0, pB1, pB2, pB3;
      if (ksl < 2) {
        pA0 = s0[base + 0]; pA1 = s0[base + 1]; pA2 = s0[base + 2]; pA3 = s0[base + 3];
        pB0 = s0[base + 4]; pB1 = s0[base + 5]; pB2 = s0[base + 6]; pB3 = s0[base + 7];
      } else {
        pA0 = s1[base + 0]; pA1 = s1[base + 1]; pA2 = s1[base + 2]; pA3 = s1[base + 3];
        pB0 = s1[base + 4]; pB1 = s1[base + 5]; pB2 = s1[base + 6]; pB3 = s1[base + 7];
      }
      unsigned a01 = cvt_pk(pA0, pA1), a23 = cvt_pk(pA2, pA3);
      unsigned b01 = cvt_pk(pB0, pB1), b23 = cvt_pk(pB2, pB3);
      unsigned xa01 = __shfl_xor(a01, 32), xa23 = __shfl_xor(a23, 32);
      unsigned xb01 = __shfl_xor(b01, 32), xb23 = __shfl_xor(b23, 32);
      union { unsigned u[4]; bf16x8 v; } pf;
      pf.u[0] = hi ? xb01 : a01;
      pf.u[1] = hi ? xb23 : a23;
      pf.u[2] = hi ? b01 : xa01;
      pf.u[3] = hi ? b23 : xa23;
      bf16x8 vf0 = *(const bf16x8*)(Vt + ksl * 512);
      bf16x8 vf1 = *(const bf16x8*)(Vt + 2048 + ksl * 512);
      oa0 = __builtin_amdgcn_mfma_f32_32x32x16_bf16(vf0, pf.v, oa0, 0, 0, 0);
      oa1 = __builtin_amdgcn_mfma_f32_32x32x16_bf16(vf1, pf.v, oa1, 0, 0, 0);
    }
  }
  __syncthreads();

  // ---- merge across 4 splits (tree: {2,3}->{0,1}, then 1->0) ----
  float* mlBuf = (float*)(smem + 24576);
#define OB_BYTE(g, halfoff) (lo5 * 256 + (((halfoff) + 32 * (g) + 16 * hi) ^ ((lo5 & 15) << 4)))
  if (ks >= 2) {
    char* ob = smem + (ks - 2) * 8192;
#pragma unroll
    for (int g = 0; g < 4; ++g) {
      *(float4*)(ob + OB_BYTE(g, 0)) = make_float4(oa0[4 * g + 0], oa0[4 * g + 1], oa0[4 * g + 2], oa0[4 * g + 3]);
      *(float4*)(ob + OB_BYTE(g, 128)) = make_float4(oa1[4 * g + 0], oa1[4 * g + 1], oa1[4 * g + 2], oa1[4 * g + 3]);
    }
    if (hi == 0) { mlBuf[(ks * 32 + lo5) * 2] = mrun; mlBuf[(ks * 32 + lo5) * 2 + 1] = lsum; }
  }
  __syncthreads();
  if (ks < 2) {
    int pw = ks + 2;
    char* ob = smem + ks * 8192;
    float mB = mlBuf[(pw * 32 + lo5) * 2], lB = mlBuf[(pw * 32 + lo5) * 2 + 1];
    float M = fmaxf(mrun, mB);
    float sA = exp2f(mrun - M), sB = exp2f(mB - M);
    lsum = lsum * sA + lB * sB;
    mrun = M;
#pragma unroll
    for (int g = 0; g < 4; ++g) {
      float4 v0 = *(const float4*)(ob + OB_BYTE(g, 0));
      float4 v1 = *(const float4*)(ob + OB_BYTE(g, 128));
      oa0[4 * g + 0] = oa0[4 * g + 0] * sA + v0.x * sB;
      oa0[4 * g + 1] = oa0[4 * g + 1] * sA + v0.y * sB;
      oa0[4 * g + 2] = oa0[4 * g + 2] * sA + v0.z * sB;
      oa0[4 * g + 3] = oa0[4 * g + 3] * sA + v0.w * sB;
      oa1[4 * g + 0] = oa1[4 * g + 0] * sA + v1.x * sB;
      oa1[4 * g + 1] = oa1[4 * g + 1] * sA + v1.y * sB;
      oa1[4 * g + 2] = oa1[4 * g + 2] * sA + v1.z * sB;
      oa1[4 * g + 3] = oa1[4 * g + 3] * sA + v1.w * sB;
    }
  }
  if (ks == 1) {
    char* ob = smem + 16384;
#pragma unroll
    for (int g = 0; g < 4; ++g) {
      *(float4*)(ob + OB_BYTE(g, 0)) = make_float4(oa0[4 * g + 0], oa0[4 * g + 1], oa0[4 * g + 2], oa0[4 * g + 3]);
      *(float4*)(ob + OB_BYTE(g, 128)) = make_float4(oa1[4 * g + 0], oa1[4 * g + 1], oa1[4 * g + 2], oa1[4 * g + 3]);
    }
    if (hi == 0) { mlBuf[(32 + lo5) * 2] = mrun; mlBuf[(32 + lo5) * 2 + 1] = lsum; }
  }
  __syncthreads();
  if (ks == 0) {
    char* ob = smem + 16384;
    float mB = mlBuf[(32 + lo5) * 2], lB = mlBuf[(32 + lo5) * 2 + 1];
    float M = fmaxf(mrun, mB);
    float sA = exp2f(mrun - M), sB = exp2f(mB - M);
    lsum = lsum * sA + lB * sB;
#pragma unroll
    for (int g = 0; g < 4; ++g) {
      float4 v0 = *(const float4*)(ob + OB_BYTE(g, 0));
      float4 v1 = *(const float4*)(ob + OB_BYTE(g, 128));
      oa0[4 * g + 0] = oa0[4 * g + 0] * sA + v0.x * sB;
      oa0[4 * g + 1] = oa0[4 * g + 1] * sA + v0.y * sB;
      oa0[4 * g + 2] = oa0[4 * g + 2] * sA + v0.z * sB;
      oa0[4 * g + 3] = oa0[4 * g + 3] * sA + v0.w * sB;
      oa1[4 * g + 0] = oa1[4 * g + 0] * sA + v1.x * sB;
      oa1[4 * g + 1] = oa1[4 * g + 1] * sA + v1.y * sB;
      oa1[4 * g + 2] = oa1[4 * g + 2] * sA + v1.z * sB;
      oa1[4 * g + 3] = oa1[4 * g + 3] * sA + v1.w * sB;
    }
    // ldsO (4KB) aliases ob buffer 0: last read of buffer 0 was before barrier above
    float inv = 1.f / lsum;
    u16* ldsO = (u16*)smem;
    int qrow = lo5;
#pragma unroll
    for (int g = 0; g < 4; ++g) {
      unsigned w0 = cvt_pk(oa0[4 * g + 0] * inv, oa0[4 * g + 1] * inv);
      unsigned w1 = cvt_pk(oa0[4 * g + 2] * inv, oa0[4 * g + 3] * inv);
      int dby = (8 * g + 4 * hi) * 2;
      *(uint2*)((char*)ldsO + qrow * 128 + (dby ^ ((qrow & 7) << 4))) = make_uint2(w0, w1);
      unsigned w2 = cvt_pk(oa1[4 * g + 0] * inv, oa1[4 * g + 1] * inv);
      unsigned w3 = cvt_pk(oa1[4 * g + 2] * inv, oa1[4 * g + 3] * inv);
      int dby2 = (32 + 8 * g + 4 * hi) * 2;
      *(uint2*)((char*)ldsO + qrow * 128 + (dby2 ^ ((qrow & 7) << 4))) = make_uint2(w2, w3);
    }
  }
  __syncthreads();
  {
    u16* ldsO = (u16*)smem;
    int row = t >> 3, c16 = t & 7;   // 256 thr = 32 rows x 8 chunks of 16B
    uint4 val = *(const uint4*)((const char*)ldsO + row * 128 + ((c16 * 16) ^ ((row & 7) << 4)));
    *(uint4*)(O + (size_t)(q0 + row) * 1024 + hd0 + c16 * 8) = val;
  }
#undef OB_BYTE
}

// ==========================================================================================
extern "C" void kernel_launch(void* const* d_in, const int* in_sizes, int n_in,
                              void* d_out, int out_size, void* d_ws, size_t ws_size,
                              hipStream_t stream) {
  const float* features = (const float*)d_in[0];
  const float* enc      = (const float*)d_in[1];
  const float* g1a = (const float*)d_in[2];  const float* b1a = (const float*)d_in[3];
  const float* g1b = (const float*)d_in[4];  const float* b1b = (const float*)d_in[5];
  const float* g2a = (const float*)d_in[6];  const float* b2a = (const float*)d_in[7];
  const float* g2b = (const float*)d_in[8];  const float* b2b = (const float*)d_in[9];
  const float* sa_qw = (const float*)d_in[10]; const float* sa_qb = (const float*)d_in[11];
  const float* sa_kw = (const float*)d_in[12]; const float* sa_kb = (const float*)d_in[13];
  const float* sa_vw = (const float*)d_in[14]; const float* sa_vb = (const float*)d_in[15];
  const float* sa_pw = (const float*)d_in[16]; const float* sa_pb = (const float*)d_in[17];
  const float* ca_qw = (const float*)d_in[18]; const float* ca_qb = (const float*)d_in[19];
  const float* ca_kw = (const float*)d_in[20]; const float* ca_kb = (const float*)d_in[21];
  const float* ca_vw = (const float*)d_in[22]; const float* ca_vb = (const float*)d_in[23];
  const float* ca_pw = (const float*)d_in[24]; const float* ca_pb = (const float*)d_in[25];
  const float* m1_w1 = (const float*)d_in[26]; const float* m1_b1 = (const float*)d_in[27];
  const float* m1_w2 = (const float*)d_in[28]; const float* m1_b2 = (const float*)d_in[29];
  const float* m2_w1 = (const float*)d_in[30]; const float* m2_b1 = (const float*)d_in[31];
  const float* m2_w2 = (const float*)d_in[32]; const float* m2_b2 = (const float*)d_in[33];

  const int S = 2048, C = 1024, Mh = 4096;
  const size_t CC = (size_t)C * C;
  float* xout = (float*)d_out;

  char* p = (char*)d_ws;
  auto take = [&](size_t bytes) { char* q = p; p += (bytes + 255) & ~(size_t)255; return q; };
  u16* wt_qkv  = (u16*)take(3 * CC * 2);
  u16* wt_sap  = (u16*)take(CC * 2);
  u16* wt_cap  = (u16*)take(CC * 2);
  u16* wt_caq  = (u16*)take(CC * 2);
  u16* wt_ckv  = (u16*)take(2 * CC * 2);
  u16* wt_m1w1 = (u16*)take((size_t)C * Mh * 2);
  u16* wt_m1w2 = (u16*)take((size_t)C * Mh * 2);
  u16* wt_m2w1 = (u16*)take((size_t)C * Mh * 2);
  u16* wt_m2w2 = (u16*)take((size_t)C * Mh * 2);
  float* bias_qkv = (float*)take(3 * C * 4);
  float* bias_ckv = (float*)take(2 * C * 4);
  u16* xn   = (u16*)take((size_t)S * C * 2);
  u16* encb = (u16*)take((size_t)S * C * 2);
  u16* abuf = (u16*)take((size_t)S * C * 2);
  u16* hbuf = (u16*)take((size_t)S * Mh * 2);   // 16MB: QKV frag region / MLP hidden
  u16* qsbuf = hbuf;
  u16* kf_b  = hbuf + (size_t)2 * 1024 * 1024;
  u16* vf_b  = hbuf + (size_t)4 * 1024 * 1024;

  dim3 blk(256);
  const float qs2 = 0.125f * 1.4426950408889634f;  // hd^-0.5 * log2(e)

  TransArgs ta;
  ta.src[0] = sa_qw;  ta.dst[0] = wt_qkv;
  ta.src[1] = sa_kw;  ta.dst[1] = wt_qkv + CC;
  ta.src[2] = sa_vw;  ta.dst[2] = wt_qkv + 2 * CC;
  ta.src[3] = sa_pw;  ta.dst[3] = wt_sap;
  ta.src[4] = ca_pw;  ta.dst[4] = wt_cap;
  ta.src[5] = ca_qw;  ta.dst[5] = wt_caq;
  ta.src[6] = ca_kw;  ta.dst[6] = wt_ckv;
  ta.src[7] = ca_vw;  ta.dst[7] = wt_ckv + CC;
  ta.src[8] = m1_w1;  ta.dst[8] = wt_m1w1;
  ta.src[9] = m1_w2;  ta.dst[9] = wt_m1w2;
  ta.src[10] = m2_w1; ta.dst[10] = wt_m2w1;
  ta.src[11] = m2_w2; ta.dst[11] = wt_m2w2;
  ta.enc = enc; ta.encb = encb;
  ta.bq = bias_qkv; ta.bc = bias_ckv;
  ta.qb = sa_qb; ta.kb = sa_kb; ta.vb = sa_vb; ta.ckb = ca_kb; ta.cvb = ca_vb;
  ta.feat = features; ta.g1a = g1a; ta.b1a = b1a; ta.xn = xn;
  k_prepass<<<dim3(8212 + 2048), blk, 0, stream>>>(ta);   // + LN1a rows fused

  // --- block 1: self-attention (causal); xn already produced by prepass
  k_gemm<0, 128><<<dim3(24, 16), blk, 0, stream>>>(xn, wt_qkv, bias_qkv, qsbuf, kf_b, vf_b,
                                                   S, 3072, C, 1024, 2048, qs2);
  k_attn6<true><<<dim3(16, 64), blk, 0, stream>>>(qsbuf, kf_b, vf_b, abuf, S, 1024);
  k_gemm_sk<1><<<dim3(16, 32), dim3(512), 0, stream>>>(abuf, wt_sap, sa_pb, features, xout, S, C, C, 1.f);
  // --- MLP 1
  k_ln<<<S, blk, 0, stream>>>(xout, g1b, b1b, xn);
  k_gemm<2, 128><<<dim3(32, 16), blk, 0, stream>>>(xn, wt_m1w1, m1_b1, hbuf, nullptr, nullptr,
                                                   S, Mh, C, 0, 1 << 30, 1.f);
  k_gemm_sk<1><<<dim3(16, 32), dim3(512), 0, stream>>>(hbuf, wt_m1w2, m1_b2, xout, xout, S, C, Mh, 1.f);
  // --- block 2: cross-attention
  k_ln<<<S, blk, 0, stream>>>(xout, g2a, b2a, xn);
  k_gemm_sk<0><<<dim3(16, 32), dim3(512), 0, stream>>>(xn, wt_caq, ca_qb, nullptr, qsbuf, S, C, C, qs2);
  k_gemm<0, 64><<<dim3(16, 32), blk, 0, stream>>>(encb, wt_ckv, bias_ckv, nullptr, kf_b, vf_b,
                                                  S, 2048, C, 0, 1024, 1.f);
  k_attn6<false><<<dim3(16, 64), blk, 0, stream>>>(qsbuf, kf_b, vf_b, abuf, S, 1024);
  k_gemm_sk<1><<<dim3(16, 32), dim3(512), 0, stream>>>(abuf, wt_cap, ca_pb, xout, xout, S, C, C, 1.f);
  // --- MLP 2
  k_ln<<<S, blk, 0, stream>>>(xout, g2b, b2b, xn);
  k_gemm<2, 128><<<dim3(32, 16), blk, 0, stream>>>(xn, wt_m2w1, m2_b1, hbuf, nullptr, nullptr,
                                                   S, Mh, C, 0, 1 << 30, 1.f);
  k_gemm_sk<1><<<dim3(16, 32), dim3(512), 0, stream>>>(hbuf, wt_m2w2, m2_b2, xout, xout, S, C, Mh, 1.f);
}